// Round 1
// 1419.922 us; speedup vs baseline: 1.0026x; 1.0026x over previous
//
#include <hip/hip_runtime.h>

#define NN   100000
#define NE   3200000
#define K_IN 1433
#define HID  16
#define OUTF 7

#define SCAN_CHUNK 512
#define SCAN_NB    196   // 196*512 = 100352 >= NN

typedef float f4 __attribute__((ext_vector_type(4)));

__device__ __forceinline__ f4 ld_f4u(const float* p) { f4 r; __builtin_memcpy(&r, p, 16); return r; }
__device__ __forceinline__ void st_f4u(float* p, f4 v) { __builtin_memcpy(p, &v, 16); }

// ---------------- CSR build ----------------
// 2 edges per thread: halves launch width, lets compiler use dwordx2 loads.
__global__ void count_kernel(const int* __restrict__ ei,
                             int* __restrict__ cnt_src, int* __restrict__ cnt_dst) {
    int e2 = (blockIdx.x * blockDim.x + threadIdx.x) * 2;
    if (e2 < NE) {   // NE even -> e2+1 valid whenever e2 valid
        int s0 = ei[e2], s1 = ei[e2 + 1];
        int d0 = ei[NE + e2], d1 = ei[NE + e2 + 1];
        atomicAdd(&cnt_src[s0], 1);
        atomicAdd(&cnt_src[s1], 1);
        atomicAdd(&cnt_dst[d0], 1);
        atomicAdd(&cnt_dst[d1], 1);
    }
}

// phase A: per-block (512-elem chunk) sums of cnt_dst, FUSED with norm
// (reads cnt_dst anyway; adds cnt_src read + nsrc/ndst writes, kills norm_kernel)
__global__ __launch_bounds__(256) void scanA_kernel(const int* __restrict__ cnt_dst,
                                                    const int* __restrict__ cnt_src,
                                                    int* __restrict__ partials,
                                                    float* __restrict__ nsrc,
                                                    float* __restrict__ ndst) {
    __shared__ int sh[4];
    int b = blockIdx.x, t = threadIdx.x;
    int i0 = b * SCAN_CHUNK + 2 * t;
    int v0 = (i0 < NN) ? cnt_dst[i0] : 0;
    int v1 = (i0 + 1 < NN) ? cnt_dst[i0 + 1] : 0;
    if (i0 < NN) {
        ndst[i0] = rsqrtf(fmaxf((float)v0, 1.0f));
        nsrc[i0] = rsqrtf(fmaxf((float)cnt_src[i0], 1.0f));
    }
    if (i0 + 1 < NN) {
        ndst[i0 + 1] = rsqrtf(fmaxf((float)v1, 1.0f));
        nsrc[i0 + 1] = rsqrtf(fmaxf((float)cnt_src[i0 + 1], 1.0f));
    }
    int s = v0 + v1;
    for (int d = 1; d < 64; d <<= 1) s += __shfl_xor(s, d, 64);
    if ((t & 63) == 0) sh[t >> 6] = s;
    __syncthreads();
    if (t == 0) partials[b] = sh[0] + sh[1] + sh[2] + sh[3];
}

// phase B: single block exclusive-scans the 196 partials
__global__ __launch_bounds__(256) void scanB_kernel(const int* __restrict__ partials,
                                                    int* __restrict__ base) {
    __shared__ int sh[256];
    int t = threadIdx.x;
    int v = (t < SCAN_NB) ? partials[t] : 0;
    sh[t] = v;
    __syncthreads();
    for (int d = 1; d < 256; d <<= 1) {
        int x = (t >= d) ? sh[t - d] : 0;
        __syncthreads();
        sh[t] += x;
        __syncthreads();
    }
    if (t < SCAN_NB) base[t] = sh[t] - v;   // exclusive
}

// phase C: rescan each chunk, add base, write offs + cursor
__global__ __launch_bounds__(256) void scanC_kernel(const int* __restrict__ cnt,
                                                    const int* __restrict__ base,
                                                    int* __restrict__ offs, int* __restrict__ cursor) {
    __shared__ int sh[256];
    int b = blockIdx.x, t = threadIdx.x;
    int i0 = b * SCAN_CHUNK + 2 * t;
    int v0 = (i0 < NN) ? cnt[i0] : 0;
    int v1 = (i0 + 1 < NN) ? cnt[i0 + 1] : 0;
    int s = v0 + v1;
    sh[t] = s;
    __syncthreads();
    for (int d = 1; d < 256; d <<= 1) {
        int x = (t >= d) ? sh[t - d] : 0;
        __syncthreads();
        sh[t] += x;
        __syncthreads();
    }
    int excl = sh[t] - s + base[b];
    if (i0 < NN)     { offs[i0] = excl;          cursor[i0] = excl; }
    if (i0 + 1 < NN) { offs[i0 + 1] = excl + v0; cursor[i0 + 1] = excl + v0; }
}

__global__ void fill_kernel(const int* __restrict__ ei, int* __restrict__ cursor,
                            int* __restrict__ sorted_src) {
    int e2 = (blockIdx.x * blockDim.x + threadIdx.x) * 2;
    if (e2 < NE) {
        int s0 = ei[e2], s1 = ei[e2 + 1];
        int d0 = ei[NE + e2], d1 = ei[NE + e2 + 1];
        int slot0 = atomicAdd(&cursor[d0], 1);
        int slot1 = atomicAdd(&cursor[d1], 1);
        sorted_src[slot0] = s0;
        sorted_src[slot1] = s1;
    }
}

// ---------------- layer-1 GEMM: x1 = (feat * nsrc) @ W1 ----------------
// Block = 4 waves; wave w owns cols [4w,4w+4). Lane l owns k in {4l+256i}.
// w slice = 96 VGPRs; NO explicit double-buffer (round-2 version spilled
// past the 168-VGPR cap of launch_bounds(256,3); compiler pipelines rows
// itself within the budget). 7-shuffle butterfly, disjoint stores.
__global__ __launch_bounds__(256, 3) void gemm1_kernel(
    const float* __restrict__ feat, const float* __restrict__ W1,
    const float* __restrict__ nsrc, float* __restrict__ x1)
{
    const int tid  = threadIdx.x;
    const int lane = tid & 63;
    const int wv   = tid >> 6;
    const int c0   = 4 * wv;

    const int kb5 = 1280 + 4 * lane;                       // i=5 nominal base
    const int kc5 = (kb5 > K_IN - 4) ? (K_IN - 4) : kb5;   // clamped in-row load base

    f4 w[6][4];
#pragma unroll
    for (int i = 0; i < 5; ++i) {
        int kb = 4 * lane + 256 * i;
#pragma unroll
        for (int d = 0; d < 4; ++d)
            w[i][d] = ld_f4u(W1 + (size_t)(kb + d) * HID + c0);
    }
#pragma unroll
    for (int d = 0; d < 4; ++d) {
        int keff = kc5 + d;
        f4 z = {0.f, 0.f, 0.f, 0.f};
        w[5][d] = (keff >= kb5 && keff < K_IN) ? ld_f4u(W1 + (size_t)keff * HID + c0) : z;
    }

    const int row0 = blockIdx.x * 32;
    const int row1 = min(row0 + 32, NN);

    for (int row = row0; row < row1; ++row) {
        const float* fp = feat + (size_t)row * K_IN;
        f4 f[6];
#pragma unroll
        for (int i = 0; i < 5; ++i) f[i] = ld_f4u(fp + 4 * lane + 256 * i);
        f[5] = ld_f4u(fp + kc5);

        f4 acc = {0.f, 0.f, 0.f, 0.f};
#pragma unroll
        for (int i = 0; i < 6; ++i) {
            acc += f[i].x * w[i][0];
            acc += f[i].y * w[i][1];
            acc += f[i].z * w[i][2];
            acc += f[i].w * w[i][3];
        }
        // fold 4 col-partials -> 1 per lane (2 shfl), then 4-step butterfly
        const bool b0 = lane & 1;
        float s0 = b0 ? acc.x : acc.z;
        float s1 = b0 ? acc.y : acc.w;
        float r0 = __shfl_xor(s0, 1, 64);
        float r1 = __shfl_xor(s1, 1, 64);
        float k0 = (b0 ? acc.z : acc.x) + r0;
        float k1 = (b0 ? acc.w : acc.y) + r1;
        const bool b1 = lane & 2;
        float s = b1 ? k0 : k1;
        float r = __shfl_xor(s, 2, 64);
        float v = (b1 ? k1 : k0) + r;
        v += __shfl_xor(v, 4, 64);
        v += __shfl_xor(v, 8, 64);
        v += __shfl_xor(v, 16, 64);
        v += __shfl_xor(v, 32, 64);
        if (lane < 4) {
            int cl = 2 * (lane & 1) + ((lane >> 1) & 1);   // lane -> col within group
            x1[(size_t)row * HID + c0 + cl] = v * nsrc[row];
        }
    }
}

// ---- layer-1 aggregation FUSED with layer-2 dense ----
// h[dst][4q..4q+4) = relu(ndst*sum_e x1[src] + b1)   (4 threads per dst)
// then x2[dst][c] = nsrc[dst] * sum_j h[j]*W2[j][c] via 4-lane shuffle reduce.
// x2 padded to stride 8 so agg2 gathers are 16B-aligned.
// Edge loop unrolled x4 with 2 accumulators: 4 independent gathers in flight
// per thread (was 1 -> latency-bound serial chain).
__global__ __launch_bounds__(256) void agg1_kernel(
        const int* __restrict__ offs, const int* __restrict__ cnt,
        const int* __restrict__ ssrc, const float* __restrict__ x1,
        const float* __restrict__ ndst, const float* __restrict__ nsrc,
        const float* __restrict__ b1, const float* __restrict__ W2,
        float* __restrict__ x2) {
    int t = blockIdx.x * blockDim.x + threadIdx.x;
    if (t >= NN * 4) return;          // NN*4 = 400000 = 6250 full waves; whole waves exit
    int dst = t >> 2, q = t & 3;
    int st = offs[dst], deg = cnt[dst];
    const float* xq = x1 + 4 * q;
    f4 acc0 = {0.f, 0.f, 0.f, 0.f};
    f4 acc1 = {0.f, 0.f, 0.f, 0.f};
    int e = 0;
    for (; e + 4 <= deg; e += 4) {
        int s0 = ssrc[st + e];
        int s1 = ssrc[st + e + 1];
        int s2 = ssrc[st + e + 2];
        int s3 = ssrc[st + e + 3];
        f4 v0 = *(const f4*)(xq + (size_t)s0 * HID);
        f4 v1 = *(const f4*)(xq + (size_t)s1 * HID);
        f4 v2 = *(const f4*)(xq + (size_t)s2 * HID);
        f4 v3 = *(const f4*)(xq + (size_t)s3 * HID);
        acc0 += v0; acc1 += v1; acc0 += v2; acc1 += v3;
    }
    for (; e < deg; ++e)
        acc0 += *(const f4*)(xq + (size_t)ssrc[st + e] * HID);
    f4 acc = acc0 + acc1;

    float nd = ndst[dst];
    const f4 b = *(const f4*)(b1 + 4 * q);
    f4 h = acc * nd + b;
    h.x = fmaxf(h.x, 0.f); h.y = fmaxf(h.y, 0.f);
    h.z = fmaxf(h.z, 0.f); h.w = fmaxf(h.w, 0.f);

    // fused layer-2 dense: per-lane partial over its 4 rows of W2
    float p[OUTF];
#pragma unroll
    for (int c = 0; c < OUTF; ++c) {
        const float* w = W2 + (size_t)(4 * q) * OUTF + c;
        p[c] = h.x * w[0] + h.y * w[OUTF] + h.z * w[2 * OUTF] + h.w * w[3 * OUTF];
    }
    // reduce across the 4 q-lanes of this dst (lanes l^1, l^2 are same dst)
#pragma unroll
    for (int c = 0; c < OUTF; ++c) {
        p[c] += __shfl_xor(p[c], 1, 64);
        p[c] += __shfl_xor(p[c], 2, 64);
    }
    if (q == 0) {
        float ns = nsrc[dst];
        f4 lo = {p[0] * ns, p[1] * ns, p[2] * ns, p[3] * ns};
        f4 hi = {p[4] * ns, p[5] * ns, p[6] * ns, 0.f};
        st_f4u(x2 + (size_t)dst * 8, lo);
        st_f4u(x2 + (size_t)dst * 8 + 4, hi);
    }
}

// ---- layer-2 aggregation + epilogue: out = ndst*sum_e x2[src] + b2 ----
// x2 stride 8 (padded): both q-gathers 16B-aligned, pad is 0 (finite).
__global__ void agg2_kernel(const int* __restrict__ offs, const int* __restrict__ cnt,
                            const int* __restrict__ ssrc, const float* __restrict__ x2,
                            const float* __restrict__ ndst, const float* __restrict__ b2,
                            float* __restrict__ out) {
    int t = blockIdx.x * blockDim.x + threadIdx.x;
    if (t >= NN * 2) return;
    int dst = t >> 1, q = t & 1;
    int st = offs[dst], deg = cnt[dst];
    const float* xq = x2 + 4 * q;
    f4 acc0 = {0.f, 0.f, 0.f, 0.f};
    f4 acc1 = {0.f, 0.f, 0.f, 0.f};
    int e = 0;
    for (; e + 4 <= deg; e += 4) {
        int s0 = ssrc[st + e];
        int s1 = ssrc[st + e + 1];
        int s2 = ssrc[st + e + 2];
        int s3 = ssrc[st + e + 3];
        f4 v0 = *(const f4*)(xq + (size_t)s0 * 8);
        f4 v1 = *(const f4*)(xq + (size_t)s1 * 8);
        f4 v2 = *(const f4*)(xq + (size_t)s2 * 8);
        f4 v3 = *(const f4*)(xq + (size_t)s3 * 8);
        acc0 += v0; acc1 += v1; acc0 += v2; acc1 += v3;
    }
    for (; e < deg; ++e)
        acc0 += *(const f4*)(xq + (size_t)ssrc[st + e] * 8);
    f4 acc = acc0 + acc1;
    float nd = ndst[dst];
    if (q == 0) {
        f4 b = {b2[0], b2[1], b2[2], b2[3]};
        f4 r = acc * nd + b;
        st_f4u(out + (size_t)dst * OUTF, r);
    } else {
        out[(size_t)dst * OUTF + 4] = acc.x * nd + b2[4];
        out[(size_t)dst * OUTF + 5] = acc.y * nd + b2[5];
        out[(size_t)dst * OUTF + 6] = acc.z * nd + b2[6];
    }
}

extern "C" void kernel_launch(void* const* d_in, const int* in_sizes, int n_in,
                              void* d_out, int out_size, void* d_ws, size_t ws_size,
                              hipStream_t stream) {
    const float* feat = (const float*)d_in[0];
    const int*   ei   = (const int*)d_in[1];     // [2, NE] int32
    const float* W1   = (const float*)d_in[2];
    const float* b1   = (const float*)d_in[3];
    const float* W2   = (const float*)d_in[4];
    const float* b2   = (const float*)d_in[5];
    float*       out  = (float*)d_out;

    // workspace layout (4B units)
    int*   sorted_src = (int*)d_ws;              // [NE]
    int*   cnt_src    = sorted_src + NE;         // [NN]
    int*   cnt_dst    = cnt_src + NN;            // [NN]
    int*   offs       = cnt_dst + NN;            // [NN]
    int*   cursor     = offs + NN;               // [NN]
    int*   partials   = cursor + NN;             // [256]
    int*   base       = partials + 256;          // [256]
    float* nsrc       = (float*)(base + 256);    // [NN]
    float* ndst       = nsrc + NN;               // [NN]
    float* x1         = ndst + NN;               // [16*NN]
    float* x2         = x1 + (size_t)16 * NN;    // [8*NN] padded stride-8 (own space:
                                                 //  agg1 reads x1 while writing x2)

    hipMemsetAsync(cnt_src, 0, (size_t)2 * NN * sizeof(int), stream);

    count_kernel<<<(NE / 2 + 255) / 256, 256, 0, stream>>>(ei, cnt_src, cnt_dst);
    scanA_kernel<<<SCAN_NB, 256, 0, stream>>>(cnt_dst, cnt_src, partials, nsrc, ndst);
    scanB_kernel<<<1, 256, 0, stream>>>(partials, base);
    scanC_kernel<<<SCAN_NB, 256, 0, stream>>>(cnt_dst, base, offs, cursor);
    fill_kernel<<<(NE / 2 + 255) / 256, 256, 0, stream>>>(ei, cursor, sorted_src);

    gemm1_kernel<<<(NN + 31) / 32, 256, 0, stream>>>(feat, W1, nsrc, x1);

    agg1_kernel<<<(NN * 4 + 255) / 256, 256, 0, stream>>>(offs, cnt_dst, sorted_src, x1,
                                                          ndst, nsrc, b1, W2, x2);
    agg2_kernel<<<(NN * 2 + 255) / 256, 256, 0, stream>>>(offs, cnt_dst, sorted_src, x2,
                                                          ndst, b2, out);
}

// Round 2
// 1350.671 us; speedup vs baseline: 1.0540x; 1.0513x over previous
//
#include <hip/hip_runtime.h>

#define NN   100000
#define NE   3200000
#define K_IN 1433
#define HID  16
#define OUTF 7

#define SCAN_CHUNK 512
#define SCAN_NB    196   // 196*512 = 100352 >= NN

typedef float f4 __attribute__((ext_vector_type(4)));

__device__ __forceinline__ f4 ld_f4u(const float* p) { f4 r; __builtin_memcpy(&r, p, 16); return r; }
__device__ __forceinline__ void st_f4u(float* p, f4 v) { __builtin_memcpy(p, &v, 16); }

// ---------------- CSR build ----------------
// 2 edges per thread: halves launch width, lets compiler use dwordx2 loads.
__global__ void count_kernel(const int* __restrict__ ei,
                             int* __restrict__ cnt_src, int* __restrict__ cnt_dst) {
    int e2 = (blockIdx.x * blockDim.x + threadIdx.x) * 2;
    if (e2 < NE) {   // NE even -> e2+1 valid whenever e2 valid
        int s0 = ei[e2], s1 = ei[e2 + 1];
        int d0 = ei[NE + e2], d1 = ei[NE + e2 + 1];
        atomicAdd(&cnt_src[s0], 1);
        atomicAdd(&cnt_src[s1], 1);
        atomicAdd(&cnt_dst[d0], 1);
        atomicAdd(&cnt_dst[d1], 1);
    }
}

// phase A: per-block (512-elem chunk) sums of cnt_dst, FUSED with norm
__global__ __launch_bounds__(256) void scanA_kernel(const int* __restrict__ cnt_dst,
                                                    const int* __restrict__ cnt_src,
                                                    int* __restrict__ partials,
                                                    float* __restrict__ nsrc,
                                                    float* __restrict__ ndst) {
    __shared__ int sh[4];
    int b = blockIdx.x, t = threadIdx.x;
    int i0 = b * SCAN_CHUNK + 2 * t;
    int v0 = (i0 < NN) ? cnt_dst[i0] : 0;
    int v1 = (i0 + 1 < NN) ? cnt_dst[i0 + 1] : 0;
    if (i0 < NN) {
        ndst[i0] = rsqrtf(fmaxf((float)v0, 1.0f));
        nsrc[i0] = rsqrtf(fmaxf((float)cnt_src[i0], 1.0f));
    }
    if (i0 + 1 < NN) {
        ndst[i0 + 1] = rsqrtf(fmaxf((float)v1, 1.0f));
        nsrc[i0 + 1] = rsqrtf(fmaxf((float)cnt_src[i0 + 1], 1.0f));
    }
    int s = v0 + v1;
    for (int d = 1; d < 64; d <<= 1) s += __shfl_xor(s, d, 64);
    if ((t & 63) == 0) sh[t >> 6] = s;
    __syncthreads();
    if (t == 0) partials[b] = sh[0] + sh[1] + sh[2] + sh[3];
}

// phase B: single block exclusive-scans the 196 partials
__global__ __launch_bounds__(256) void scanB_kernel(const int* __restrict__ partials,
                                                    int* __restrict__ base) {
    __shared__ int sh[256];
    int t = threadIdx.x;
    int v = (t < SCAN_NB) ? partials[t] : 0;
    sh[t] = v;
    __syncthreads();
    for (int d = 1; d < 256; d <<= 1) {
        int x = (t >= d) ? sh[t - d] : 0;
        __syncthreads();
        sh[t] += x;
        __syncthreads();
    }
    if (t < SCAN_NB) base[t] = sh[t] - v;   // exclusive
}

// phase C: rescan each chunk, add base, write offs + cursor
__global__ __launch_bounds__(256) void scanC_kernel(const int* __restrict__ cnt,
                                                    const int* __restrict__ base,
                                                    int* __restrict__ offs, int* __restrict__ cursor) {
    __shared__ int sh[256];
    int b = blockIdx.x, t = threadIdx.x;
    int i0 = b * SCAN_CHUNK + 2 * t;
    int v0 = (i0 < NN) ? cnt[i0] : 0;
    int v1 = (i0 + 1 < NN) ? cnt[i0 + 1] : 0;
    int s = v0 + v1;
    sh[t] = s;
    __syncthreads();
    for (int d = 1; d < 256; d <<= 1) {
        int x = (t >= d) ? sh[t - d] : 0;
        __syncthreads();
        sh[t] += x;
        __syncthreads();
    }
    int excl = sh[t] - s + base[b];
    if (i0 < NN)     { offs[i0] = excl;          cursor[i0] = excl; }
    if (i0 + 1 < NN) { offs[i0 + 1] = excl + v0; cursor[i0 + 1] = excl + v0; }
}

__global__ void fill_kernel(const int* __restrict__ ei, int* __restrict__ cursor,
                            int* __restrict__ sorted_src) {
    int e2 = (blockIdx.x * blockDim.x + threadIdx.x) * 2;
    if (e2 < NE) {
        int s0 = ei[e2], s1 = ei[e2 + 1];
        int d0 = ei[NE + e2], d1 = ei[NE + e2 + 1];
        int slot0 = atomicAdd(&cursor[d0], 1);
        int slot1 = atomicAdd(&cursor[d1], 1);
        sorted_src[slot0] = s0;
        sorted_src[slot1] = s1;
    }
}

// ---------------- layer-1 GEMM: x1 = (feat * nsrc) @ W1 ----------------
// v3: LDS-staged rows. Previously all 4 waves of a block streamed the SAME
// feat row through L1 (4x re-read; if the waves drift, up to 4x L2/HBM
// re-fetch = +1.7 GB). Now: groups of 4 rows; wave w loads row (4g+w) from
// global exactly ONCE (reg-staged, rows are only 4B-aligned so
// global_load_lds can't be used), ds_write_b128 into a double-buffered
// 2x4x1536f LDS slab (48 KB -> still 3 blocks/CU), one barrier per group.
// Next group's global loads are issued right after the barrier so the
// compiler hides HBM latency under the 4-row FMA+butterfly compute.
// Per-group hazards: dswrite(g) targets buf g&1 while laggard waves still
// read buf (g-1)&1 (disjoint); rewrite of buf g&1 at g+2 is fenced by the
// barrier at g+1. Row-slot layout: k = 4*lane + 256*j for j<5; slot 5 at
// 1280+4*lane holds the CLAMPED quad (kc5), masked by w[5] zeroing as before.
__global__ __launch_bounds__(256, 3) void gemm1_kernel(
    const float* __restrict__ feat, const float* __restrict__ W1,
    const float* __restrict__ nsrc, float* __restrict__ x1)
{
    __shared__ __align__(16) float lds[2][4][1536];   // 48 KB
    const int tid  = threadIdx.x;
    const int lane = tid & 63;
    const int wv   = tid >> 6;
    const int c0   = 4 * wv;

    const int kb5 = 1280 + 4 * lane;                       // slot-5 nominal base
    const int kc5 = (kb5 > K_IN - 4) ? (K_IN - 4) : kb5;   // clamped in-row load base

    f4 w[6][4];
#pragma unroll
    for (int i = 0; i < 5; ++i) {
        int kb = 4 * lane + 256 * i;
#pragma unroll
        for (int d = 0; d < 4; ++d)
            w[i][d] = ld_f4u(W1 + (size_t)(kb + d) * HID + c0);
    }
#pragma unroll
    for (int d = 0; d < 4; ++d) {
        int keff = kc5 + d;
        f4 z = {0.f, 0.f, 0.f, 0.f};
        w[5][d] = (keff >= kb5 && keff < K_IN) ? ld_f4u(W1 + (size_t)keff * HID + c0) : z;
    }

    const int row0 = blockIdx.x * 32;   // NN = 3125*32 exactly, no tail

    // prologue: stage group 0 (wave wv owns row row0+wv)
    f4 tmp[6];
    {
        const float* fp = feat + (size_t)(row0 + wv) * K_IN;
#pragma unroll
        for (int j = 0; j < 5; ++j) tmp[j] = ld_f4u(fp + 4 * lane + 256 * j);
        tmp[5] = ld_f4u(fp + kc5);
    }

    for (int g = 0; g < 8; ++g) {
        const int cur = g & 1;
        // write staged row to LDS (ds_write_b128, canonical conflict-free)
        {
            float* slot = &lds[cur][wv][0];
#pragma unroll
            for (int j = 0; j < 5; ++j) st_f4u(slot + 4 * lane + 256 * j, tmp[j]);
            st_f4u(slot + 1280 + 4 * lane, tmp[5]);
        }
        __syncthreads();
        // issue next group's global loads AFTER the barrier: consumed only at
        // the next iteration's ds_write, so ~4 rows of compute hides HBM latency
        if (g + 1 < 8) {
            const float* fp = feat + (size_t)(row0 + 4 * (g + 1) + wv) * K_IN;
#pragma unroll
            for (int j = 0; j < 5; ++j) tmp[j] = ld_f4u(fp + 4 * lane + 256 * j);
            tmp[5] = ld_f4u(fp + kc5);
        }
#pragma unroll
        for (int r = 0; r < 4; ++r) {
            const int row = row0 + 4 * g + r;
            const float* ls = &lds[cur][r][0];
            f4 f[6];
#pragma unroll
            for (int i = 0; i < 5; ++i) f[i] = *(const f4*)(ls + 4 * lane + 256 * i);
            f[5] = *(const f4*)(ls + 1280 + 4 * lane);

            f4 acc = {0.f, 0.f, 0.f, 0.f};
#pragma unroll
            for (int i = 0; i < 6; ++i) {
                acc += f[i].x * w[i][0];
                acc += f[i].y * w[i][1];
                acc += f[i].z * w[i][2];
                acc += f[i].w * w[i][3];
            }
            // fold 4 col-partials -> 1 per lane (2 shfl), then 4-step butterfly
            const bool b0 = lane & 1;
            float s0 = b0 ? acc.x : acc.z;
            float s1 = b0 ? acc.y : acc.w;
            float r0 = __shfl_xor(s0, 1, 64);
            float r1 = __shfl_xor(s1, 1, 64);
            float k0 = (b0 ? acc.z : acc.x) + r0;
            float k1 = (b0 ? acc.w : acc.y) + r1;
            const bool b1 = lane & 2;
            float s = b1 ? k0 : k1;
            float rr = __shfl_xor(s, 2, 64);
            float v = (b1 ? k1 : k0) + rr;
            v += __shfl_xor(v, 4, 64);
            v += __shfl_xor(v, 8, 64);
            v += __shfl_xor(v, 16, 64);
            v += __shfl_xor(v, 32, 64);
            if (lane < 4) {
                int cl = 2 * (lane & 1) + ((lane >> 1) & 1);   // lane -> col within group
                x1[(size_t)row * HID + c0 + cl] = v * nsrc[row];
            }
        }
    }
}

// ---- layer-1 aggregation FUSED with layer-2 dense ----
__global__ __launch_bounds__(256) void agg1_kernel(
        const int* __restrict__ offs, const int* __restrict__ cnt,
        const int* __restrict__ ssrc, const float* __restrict__ x1,
        const float* __restrict__ ndst, const float* __restrict__ nsrc,
        const float* __restrict__ b1, const float* __restrict__ W2,
        float* __restrict__ x2) {
    int t = blockIdx.x * blockDim.x + threadIdx.x;
    if (t >= NN * 4) return;
    int dst = t >> 2, q = t & 3;
    int st = offs[dst], deg = cnt[dst];
    const float* xq = x1 + 4 * q;
    f4 acc0 = {0.f, 0.f, 0.f, 0.f};
    f4 acc1 = {0.f, 0.f, 0.f, 0.f};
    int e = 0;
    for (; e + 4 <= deg; e += 4) {
        int s0 = ssrc[st + e];
        int s1 = ssrc[st + e + 1];
        int s2 = ssrc[st + e + 2];
        int s3 = ssrc[st + e + 3];
        f4 v0 = *(const f4*)(xq + (size_t)s0 * HID);
        f4 v1 = *(const f4*)(xq + (size_t)s1 * HID);
        f4 v2 = *(const f4*)(xq + (size_t)s2 * HID);
        f4 v3 = *(const f4*)(xq + (size_t)s3 * HID);
        acc0 += v0; acc1 += v1; acc0 += v2; acc1 += v3;
    }
    for (; e < deg; ++e)
        acc0 += *(const f4*)(xq + (size_t)ssrc[st + e] * HID);
    f4 acc = acc0 + acc1;

    float nd = ndst[dst];
    const f4 b = *(const f4*)(b1 + 4 * q);
    f4 h = acc * nd + b;
    h.x = fmaxf(h.x, 0.f); h.y = fmaxf(h.y, 0.f);
    h.z = fmaxf(h.z, 0.f); h.w = fmaxf(h.w, 0.f);

    float p[OUTF];
#pragma unroll
    for (int c = 0; c < OUTF; ++c) {
        const float* w = W2 + (size_t)(4 * q) * OUTF + c;
        p[c] = h.x * w[0] + h.y * w[OUTF] + h.z * w[2 * OUTF] + h.w * w[3 * OUTF];
    }
#pragma unroll
    for (int c = 0; c < OUTF; ++c) {
        p[c] += __shfl_xor(p[c], 1, 64);
        p[c] += __shfl_xor(p[c], 2, 64);
    }
    if (q == 0) {
        float ns = nsrc[dst];
        f4 lo = {p[0] * ns, p[1] * ns, p[2] * ns, p[3] * ns};
        f4 hi = {p[4] * ns, p[5] * ns, p[6] * ns, 0.f};
        st_f4u(x2 + (size_t)dst * 8, lo);
        st_f4u(x2 + (size_t)dst * 8 + 4, hi);
    }
}

// ---- layer-2 aggregation + epilogue: out = ndst*sum_e x2[src] + b2 ----
__global__ void agg2_kernel(const int* __restrict__ offs, const int* __restrict__ cnt,
                            const int* __restrict__ ssrc, const float* __restrict__ x2,
                            const float* __restrict__ ndst, const float* __restrict__ b2,
                            float* __restrict__ out) {
    int t = blockIdx.x * blockDim.x + threadIdx.x;
    if (t >= NN * 2) return;
    int dst = t >> 1, q = t & 1;
    int st = offs[dst], deg = cnt[dst];
    const float* xq = x2 + 4 * q;
    f4 acc0 = {0.f, 0.f, 0.f, 0.f};
    f4 acc1 = {0.f, 0.f, 0.f, 0.f};
    int e = 0;
    for (; e + 4 <= deg; e += 4) {
        int s0 = ssrc[st + e];
        int s1 = ssrc[st + e + 1];
        int s2 = ssrc[st + e + 2];
        int s3 = ssrc[st + e + 3];
        f4 v0 = *(const f4*)(xq + (size_t)s0 * 8);
        f4 v1 = *(const f4*)(xq + (size_t)s1 * 8);
        f4 v2 = *(const f4*)(xq + (size_t)s2 * 8);
        f4 v3 = *(const f4*)(xq + (size_t)s3 * 8);
        acc0 += v0; acc1 += v1; acc0 += v2; acc1 += v3;
    }
    for (; e < deg; ++e)
        acc0 += *(const f4*)(xq + (size_t)ssrc[st + e] * 8);
    f4 acc = acc0 + acc1;
    float nd = ndst[dst];
    if (q == 0) {
        f4 b = {b2[0], b2[1], b2[2], b2[3]};
        f4 r = acc * nd + b;
        st_f4u(out + (size_t)dst * OUTF, r);
    } else {
        out[(size_t)dst * OUTF + 4] = acc.x * nd + b2[4];
        out[(size_t)dst * OUTF + 5] = acc.y * nd + b2[5];
        out[(size_t)dst * OUTF + 6] = acc.z * nd + b2[6];
    }
}

extern "C" void kernel_launch(void* const* d_in, const int* in_sizes, int n_in,
                              void* d_out, int out_size, void* d_ws, size_t ws_size,
                              hipStream_t stream) {
    const float* feat = (const float*)d_in[0];
    const int*   ei   = (const int*)d_in[1];     // [2, NE] int32
    const float* W1   = (const float*)d_in[2];
    const float* b1   = (const float*)d_in[3];
    const float* W2   = (const float*)d_in[4];
    const float* b2   = (const float*)d_in[5];
    float*       out  = (float*)d_out;

    // workspace layout (4B units)
    int*   sorted_src = (int*)d_ws;              // [NE]
    int*   cnt_src    = sorted_src + NE;         // [NN]
    int*   cnt_dst    = cnt_src + NN;            // [NN]
    int*   offs       = cnt_dst + NN;            // [NN]
    int*   cursor     = offs + NN;               // [NN]
    int*   partials   = cursor + NN;             // [256]
    int*   base       = partials + 256;          // [256]
    float* nsrc       = (float*)(base + 256);    // [NN]
    float* ndst       = nsrc + NN;               // [NN]
    float* x1         = ndst + NN;               // [16*NN]
    float* x2         = x1 + (size_t)16 * NN;    // [8*NN] padded stride-8

    hipMemsetAsync(cnt_src, 0, (size_t)2 * NN * sizeof(int), stream);

    count_kernel<<<(NE / 2 + 255) / 256, 256, 0, stream>>>(ei, cnt_src, cnt_dst);
    scanA_kernel<<<SCAN_NB, 256, 0, stream>>>(cnt_dst, cnt_src, partials, nsrc, ndst);
    scanB_kernel<<<1, 256, 0, stream>>>(partials, base);
    scanC_kernel<<<SCAN_NB, 256, 0, stream>>>(cnt_dst, base, offs, cursor);
    fill_kernel<<<(NE / 2 + 255) / 256, 256, 0, stream>>>(ei, cursor, sorted_src);

    gemm1_kernel<<<(NN + 31) / 32, 256, 0, stream>>>(feat, W1, nsrc, x1);

    agg1_kernel<<<(NN * 4 + 255) / 256, 256, 0, stream>>>(offs, cnt_dst, sorted_src, x1,
                                                          ndst, nsrc, b1, W2, x2);
    agg2_kernel<<<(NN * 2 + 255) / 256, 256, 0, stream>>>(offs, cnt_dst, sorted_src, x2,
                                                          ndst, b2, out);
}

// Round 4
// 1271.372 us; speedup vs baseline: 1.1197x; 1.0624x over previous
//
#include <hip/hip_runtime.h>

#define NN   100000
#define NE   3200000
#define K_IN 1433
#define HID  16
#define OUTF 7

#define SCAN_CHUNK 512
#define SCAN_NB    196   // 196*512 = 100352 >= NN

// fat-kernel partition: 3125 gemm units (32 rows each) split 1000/2125 so
// count (~25us) hides under gemm-part1 and fill (~40us) under part2.
#define GEMM_P1  1000
#define GEMM_P2  2125
#define EDGE_NB  3125    // NE / (256*4)

typedef float f4 __attribute__((ext_vector_type(4)));

__device__ __forceinline__ f4 ld_f4u(const float* p) { f4 r; __builtin_memcpy(&r, p, 16); return r; }
__device__ __forceinline__ void st_f4u(float* p, f4 v) { __builtin_memcpy(p, &v, 16); }

// ---------------- gemm unit: 32 rows of x1 = feat @ W1 (UNSCALED) ----------------
// LDS-staged (one global read per feat row), double-buffered, 4 waves x 4 cols.
// nsrc scaling moved to agg1 (per-edge) so gemm has NO dependence on the CSR
// build and can run concurrently with count/fill in the fat kernels.
__device__ __forceinline__ void gemm_unit(const float* __restrict__ feat,
                                          const float* __restrict__ W1,
                                          float* __restrict__ x1,
                                          float (*lds)[4][1536], int unit) {
    const int tid  = threadIdx.x;
    const int lane = tid & 63;
    const int wv   = tid >> 6;
    const int c0   = 4 * wv;

    const int kb5 = 1280 + 4 * lane;                       // slot-5 nominal base
    const int kc5 = (kb5 > K_IN - 4) ? (K_IN - 4) : kb5;   // clamped in-row load base

    f4 w[6][4];
#pragma unroll
    for (int i = 0; i < 5; ++i) {
        int kb = 4 * lane + 256 * i;
#pragma unroll
        for (int d = 0; d < 4; ++d)
            w[i][d] = ld_f4u(W1 + (size_t)(kb + d) * HID + c0);
    }
#pragma unroll
    for (int d = 0; d < 4; ++d) {
        int keff = kc5 + d;
        f4 z = {0.f, 0.f, 0.f, 0.f};
        w[5][d] = (keff >= kb5 && keff < K_IN) ? ld_f4u(W1 + (size_t)keff * HID + c0) : z;
    }

    const int row0 = unit * 32;

    f4 tmp[6];
    {
        const float* fp = feat + (size_t)(row0 + wv) * K_IN;
#pragma unroll
        for (int j = 0; j < 5; ++j) tmp[j] = ld_f4u(fp + 4 * lane + 256 * j);
        tmp[5] = ld_f4u(fp + kc5);
    }

    for (int g = 0; g < 8; ++g) {
        const int cur = g & 1;
        {
            float* slot = &lds[cur][wv][0];
#pragma unroll
            for (int j = 0; j < 5; ++j) st_f4u(slot + 4 * lane + 256 * j, tmp[j]);
            st_f4u(slot + 1280 + 4 * lane, tmp[5]);
        }
        __syncthreads();
        if (g + 1 < 8) {
            const float* fp = feat + (size_t)(row0 + 4 * (g + 1) + wv) * K_IN;
#pragma unroll
            for (int j = 0; j < 5; ++j) tmp[j] = ld_f4u(fp + 4 * lane + 256 * j);
            tmp[5] = ld_f4u(fp + kc5);
        }
#pragma unroll
        for (int r = 0; r < 4; ++r) {
            const int row = row0 + 4 * g + r;
            const float* ls = &lds[cur][r][0];
            f4 f[6];
#pragma unroll
            for (int i = 0; i < 5; ++i) f[i] = *(const f4*)(ls + 4 * lane + 256 * i);
            f[5] = *(const f4*)(ls + 1280 + 4 * lane);

            f4 acc = {0.f, 0.f, 0.f, 0.f};
#pragma unroll
            for (int i = 0; i < 6; ++i) {
                acc += f[i].x * w[i][0];
                acc += f[i].y * w[i][1];
                acc += f[i].z * w[i][2];
                acc += f[i].w * w[i][3];
            }
            const bool b0 = lane & 1;
            float s0 = b0 ? acc.x : acc.z;
            float s1 = b0 ? acc.y : acc.w;
            float r0 = __shfl_xor(s0, 1, 64);
            float r1 = __shfl_xor(s1, 1, 64);
            float k0 = (b0 ? acc.z : acc.x) + r0;
            float k1 = (b0 ? acc.w : acc.y) + r1;
            const bool b1 = lane & 2;
            float s = b1 ? k0 : k1;
            float rr = __shfl_xor(s, 2, 64);
            float v = (b1 ? k1 : k0) + rr;
            v += __shfl_xor(v, 4, 64);
            v += __shfl_xor(v, 8, 64);
            v += __shfl_xor(v, 16, 64);
            v += __shfl_xor(v, 32, 64);
            if (lane < 4) {
                int cl = 2 * (lane & 1) + ((lane >> 1) & 1);
                x1[(size_t)row * HID + c0 + cl] = v;   // unscaled
            }
        }
    }
}

// ---------------- fat1: gemm units [0,GEMM_P1) || count (4 edges/thread) ----------------
__global__ __launch_bounds__(256, 3) void fat1_kernel(
    const float* __restrict__ feat, const float* __restrict__ W1,
    float* __restrict__ x1, const int* __restrict__ ei,
    int* __restrict__ cnt_src, int* __restrict__ cnt_dst)
{
    __shared__ __align__(16) float lds[2][4][1536];   // 48 KB (gemm path only)
    int bid = blockIdx.x;
    if (bid < GEMM_P1) {
        gemm_unit(feat, W1, x1, lds, bid);
    } else {
        int e4 = (bid - GEMM_P1) * 1024 + threadIdx.x * 4;
        if (e4 < NE) {
            int4 s = *(const int4*)(ei + e4);
            int4 d = *(const int4*)(ei + NE + e4);
            atomicAdd(&cnt_src[s.x], 1);
            atomicAdd(&cnt_src[s.y], 1);
            atomicAdd(&cnt_src[s.z], 1);
            atomicAdd(&cnt_src[s.w], 1);
            atomicAdd(&cnt_dst[d.x], 1);
            atomicAdd(&cnt_dst[d.y], 1);
            atomicAdd(&cnt_dst[d.z], 1);
            atomicAdd(&cnt_dst[d.w], 1);
        }
    }
}

// ---------------- fat2: gemm units [GEMM_P1,3125) || fill (4 edges/thread) ----------------
__global__ __launch_bounds__(256, 3) void fat2_kernel(
    const float* __restrict__ feat, const float* __restrict__ W1,
    float* __restrict__ x1, const int* __restrict__ ei,
    int* __restrict__ cursor, int* __restrict__ sorted_src)
{
    __shared__ __align__(16) float lds[2][4][1536];
    int bid = blockIdx.x;
    if (bid < GEMM_P2) {
        gemm_unit(feat, W1, x1, lds, GEMM_P1 + bid);
    } else {
        int e4 = (bid - GEMM_P2) * 1024 + threadIdx.x * 4;
        if (e4 < NE) {
            int4 s = *(const int4*)(ei + e4);
            int4 d = *(const int4*)(ei + NE + e4);
            int slot0 = atomicAdd(&cursor[d.x], 1);
            int slot1 = atomicAdd(&cursor[d.y], 1);
            int slot2 = atomicAdd(&cursor[d.z], 1);
            int slot3 = atomicAdd(&cursor[d.w], 1);
            sorted_src[slot0] = s.x;
            sorted_src[slot1] = s.y;
            sorted_src[slot2] = s.z;
            sorted_src[slot3] = s.w;
        }
    }
}

// phase A: per-block (512-elem chunk) sums of cnt_dst, FUSED with norm
__global__ __launch_bounds__(256) void scanA_kernel(const int* __restrict__ cnt_dst,
                                                    const int* __restrict__ cnt_src,
                                                    int* __restrict__ partials,
                                                    float* __restrict__ nsrc,
                                                    float* __restrict__ ndst) {
    __shared__ int sh[4];
    int b = blockIdx.x, t = threadIdx.x;
    int i0 = b * SCAN_CHUNK + 2 * t;
    int v0 = (i0 < NN) ? cnt_dst[i0] : 0;
    int v1 = (i0 + 1 < NN) ? cnt_dst[i0 + 1] : 0;
    if (i0 < NN) {
        ndst[i0] = rsqrtf(fmaxf((float)v0, 1.0f));
        nsrc[i0] = rsqrtf(fmaxf((float)cnt_src[i0], 1.0f));
    }
    if (i0 + 1 < NN) {
        ndst[i0 + 1] = rsqrtf(fmaxf((float)v1, 1.0f));
        nsrc[i0 + 1] = rsqrtf(fmaxf((float)cnt_src[i0 + 1], 1.0f));
    }
    int s = v0 + v1;
    for (int d = 1; d < 64; d <<= 1) s += __shfl_xor(s, d, 64);
    if ((t & 63) == 0) sh[t >> 6] = s;
    __syncthreads();
    if (t == 0) partials[b] = sh[0] + sh[1] + sh[2] + sh[3];
}

// phase B: single block exclusive-scans the 196 partials
__global__ __launch_bounds__(256) void scanB_kernel(const int* __restrict__ partials,
                                                    int* __restrict__ base) {
    __shared__ int sh[256];
    int t = threadIdx.x;
    int v = (t < SCAN_NB) ? partials[t] : 0;
    sh[t] = v;
    __syncthreads();
    for (int d = 1; d < 256; d <<= 1) {
        int x = (t >= d) ? sh[t - d] : 0;
        __syncthreads();
        sh[t] += x;
        __syncthreads();
    }
    if (t < SCAN_NB) base[t] = sh[t] - v;   // exclusive
}

// phase C: rescan each chunk, add base, write offs + cursor
__global__ __launch_bounds__(256) void scanC_kernel(const int* __restrict__ cnt,
                                                    const int* __restrict__ base,
                                                    int* __restrict__ offs, int* __restrict__ cursor) {
    __shared__ int sh[256];
    int b = blockIdx.x, t = threadIdx.x;
    int i0 = b * SCAN_CHUNK + 2 * t;
    int v0 = (i0 < NN) ? cnt[i0] : 0;
    int v1 = (i0 + 1 < NN) ? cnt[i0 + 1] : 0;
    int s = v0 + v1;
    sh[t] = s;
    __syncthreads();
    for (int d = 1; d < 256; d <<= 1) {
        int x = (t >= d) ? sh[t - d] : 0;
        __syncthreads();
        sh[t] += x;
        __syncthreads();
    }
    int excl = sh[t] - s + base[b];
    if (i0 < NN)     { offs[i0] = excl;          cursor[i0] = excl; }
    if (i0 + 1 < NN) { offs[i0 + 1] = excl + v0; cursor[i0 + 1] = excl + v0; }
}

// ---- layer-1 aggregation FUSED with layer-2 dense ----
// x1 is UNSCALED; per-edge nsrc[src] scaling (same math, reordered).
__global__ __launch_bounds__(256) void agg1_kernel(
        const int* __restrict__ offs, const int* __restrict__ cnt,
        const int* __restrict__ ssrc, const float* __restrict__ x1,
        const float* __restrict__ ndst, const float* __restrict__ nsrc,
        const float* __restrict__ b1, const float* __restrict__ W2,
        float* __restrict__ x2) {
    int t = blockIdx.x * blockDim.x + threadIdx.x;
    if (t >= NN * 4) return;
    int dst = t >> 2, q = t & 3;
    int st = offs[dst], deg = cnt[dst];
    const float* xq = x1 + 4 * q;
    f4 acc0 = {0.f, 0.f, 0.f, 0.f};
    f4 acc1 = {0.f, 0.f, 0.f, 0.f};
    int e = 0;
    for (; e + 4 <= deg; e += 4) {
        int s0 = ssrc[st + e];
        int s1 = ssrc[st + e + 1];
        int s2 = ssrc[st + e + 2];
        int s3 = ssrc[st + e + 3];
        float n0 = nsrc[s0], n1 = nsrc[s1], n2 = nsrc[s2], n3 = nsrc[s3];
        f4 v0 = *(const f4*)(xq + (size_t)s0 * HID);
        f4 v1 = *(const f4*)(xq + (size_t)s1 * HID);
        f4 v2 = *(const f4*)(xq + (size_t)s2 * HID);
        f4 v3 = *(const f4*)(xq + (size_t)s3 * HID);
        acc0 += v0 * n0; acc1 += v1 * n1; acc0 += v2 * n2; acc1 += v3 * n3;
    }
    for (; e < deg; ++e) {
        int s = ssrc[st + e];
        acc0 += *(const f4*)(xq + (size_t)s * HID) * nsrc[s];
    }
    f4 acc = acc0 + acc1;

    float nd = ndst[dst];
    const f4 b = *(const f4*)(b1 + 4 * q);
    f4 h = acc * nd + b;
    h.x = fmaxf(h.x, 0.f); h.y = fmaxf(h.y, 0.f);
    h.z = fmaxf(h.z, 0.f); h.w = fmaxf(h.w, 0.f);

    float p[OUTF];
#pragma unroll
    for (int c = 0; c < OUTF; ++c) {
        const float* w = W2 + (size_t)(4 * q) * OUTF + c;
        p[c] = h.x * w[0] + h.y * w[OUTF] + h.z * w[2 * OUTF] + h.w * w[3 * OUTF];
    }
#pragma unroll
    for (int c = 0; c < OUTF; ++c) {
        p[c] += __shfl_xor(p[c], 1, 64);
        p[c] += __shfl_xor(p[c], 2, 64);
    }
    if (q == 0) {
        float ns = nsrc[dst];
        f4 lo = {p[0] * ns, p[1] * ns, p[2] * ns, p[3] * ns};
        f4 hi = {p[4] * ns, p[5] * ns, p[6] * ns, 0.f};
        st_f4u(x2 + (size_t)dst * 8, lo);
        st_f4u(x2 + (size_t)dst * 8 + 4, hi);
    }
}

// ---- layer-2 aggregation + epilogue: out = ndst*sum_e x2[src] + b2 ----
__global__ void agg2_kernel(const int* __restrict__ offs, const int* __restrict__ cnt,
                            const int* __restrict__ ssrc, const float* __restrict__ x2,
                            const float* __restrict__ ndst, const float* __restrict__ b2,
                            float* __restrict__ out) {
    int t = blockIdx.x * blockDim.x + threadIdx.x;
    if (t >= NN * 2) return;
    int dst = t >> 1, q = t & 1;
    int st = offs[dst], deg = cnt[dst];
    const float* xq = x2 + 4 * q;
    f4 acc0 = {0.f, 0.f, 0.f, 0.f};
    f4 acc1 = {0.f, 0.f, 0.f, 0.f};
    int e = 0;
    for (; e + 4 <= deg; e += 4) {
        int s0 = ssrc[st + e];
        int s1 = ssrc[st + e + 1];
        int s2 = ssrc[st + e + 2];
        int s3 = ssrc[st + e + 3];
        f4 v0 = *(const f4*)(xq + (size_t)s0 * 8);
        f4 v1 = *(const f4*)(xq + (size_t)s1 * 8);
        f4 v2 = *(const f4*)(xq + (size_t)s2 * 8);
        f4 v3 = *(const f4*)(xq + (size_t)s3 * 8);
        acc0 += v0; acc1 += v1; acc0 += v2; acc1 += v3;
    }
    for (; e < deg; ++e)
        acc0 += *(const f4*)(xq + (size_t)ssrc[st + e] * 8);
    f4 acc = acc0 + acc1;
    float nd = ndst[dst];
    if (q == 0) {
        f4 b = {b2[0], b2[1], b2[2], b2[3]};
        f4 r = acc * nd + b;
        st_f4u(out + (size_t)dst * OUTF, r);
    } else {
        out[(size_t)dst * OUTF + 4] = acc.x * nd + b2[4];
        out[(size_t)dst * OUTF + 5] = acc.y * nd + b2[5];
        out[(size_t)dst * OUTF + 6] = acc.z * nd + b2[6];
    }
}

extern "C" void kernel_launch(void* const* d_in, const int* in_sizes, int n_in,
                              void* d_out, int out_size, void* d_ws, size_t ws_size,
                              hipStream_t stream) {
    const float* feat = (const float*)d_in[0];
    const int*   ei   = (const int*)d_in[1];     // [2, NE] int32
    const float* W1   = (const float*)d_in[2];
    const float* b1   = (const float*)d_in[3];
    const float* W2   = (const float*)d_in[4];
    const float* b2   = (const float*)d_in[5];
    float*       out  = (float*)d_out;

    // workspace layout (4B units)
    int*   sorted_src = (int*)d_ws;              // [NE]
    int*   cnt_src    = sorted_src + NE;         // [NN]
    int*   cnt_dst    = cnt_src + NN;            // [NN]
    int*   offs       = cnt_dst + NN;            // [NN]
    int*   cursor     = offs + NN;               // [NN]
    int*   partials   = cursor + NN;             // [256]
    int*   base       = partials + 256;          // [256]
    float* nsrc       = (float*)(base + 256);    // [NN]
    float* ndst       = nsrc + NN;               // [NN]
    float* x1         = ndst + NN;               // [16*NN] unscaled feat@W1
    float* x2         = x1 + (size_t)16 * NN;    // [8*NN] padded stride-8

    hipMemsetAsync(cnt_src, 0, (size_t)2 * NN * sizeof(int), stream);

    // fat1: gemm part1 (blocks 0..999) runs concurrently with count
    fat1_kernel<<<GEMM_P1 + EDGE_NB, 256, 0, stream>>>(feat, W1, x1, ei, cnt_src, cnt_dst);
    scanA_kernel<<<SCAN_NB, 256, 0, stream>>>(cnt_dst, cnt_src, partials, nsrc, ndst);
    scanB_kernel<<<1, 256, 0, stream>>>(partials, base);
    scanC_kernel<<<SCAN_NB, 256, 0, stream>>>(cnt_dst, base, offs, cursor);
    // fat2: gemm part2 (blocks 0..2124) runs concurrently with fill
    fat2_kernel<<<GEMM_P2 + EDGE_NB, 256, 0, stream>>>(feat, W1, x1, ei, cursor, sorted_src);

    agg1_kernel<<<(NN * 4 + 255) / 256, 256, 0, stream>>>(offs, cnt_dst, sorted_src, x1,
                                                          ndst, nsrc, b1, W2, x2);
    agg2_kernel<<<(NN * 2 + 255) / 256, 256, 0, stream>>>(offs, cnt_dst, sorted_src, x2,
                                                          ndst, b2, out);
}